// Round 2
// 225.951 us; speedup vs baseline: 1.0179x; 1.0179x over previous
//
#include <hip/hip_runtime.h>

#define B_  4
#define N_  4096
#define H_  16
#define BH_ 64
#define S_  16
#define HS_ 4
#define ST_ 72          // f16 stride of LDS tiles: 144 B rows (16B-aligned, even frag banks)
#define EPS_ 1e-6f

typedef _Float16 h2  __attribute__((ext_vector_type(2)));
typedef _Float16 h8  __attribute__((ext_vector_type(8)));
typedef float    f4v __attribute__((ext_vector_type(4)));

struct H2x2 { h2 a, b; };
struct H2x4 { h2 e[4]; };

__device__ __forceinline__ h8 ld_h8(const _Float16* p) {
    f4v r = *(const f4v*)p;                       // ds_read_b128
    return __builtin_bit_cast(h8, r);
}
__device__ __forceinline__ H2x4 ld_h2x4(const _Float16* p) {
    f4v r = *(const f4v*)p;
    return __builtin_bit_cast(H2x4, r);
}
__device__ __forceinline__ void st_h2x2(_Float16* p, h2 a, h2 b) {
    H2x2 t{a, b};
    *(float2*)p = __builtin_bit_cast(float2, t);  // ds_write_b64
}
__device__ __forceinline__ float phi(float x) {
    return x > 0.0f ? x + 1.0f : __expf(x);       // elu(x)+1
}
__device__ __forceinline__ float fdot2(h2 a, h2 b, float c) {
    return __builtin_amdgcn_fdot2(a, b, c, false);
}
// Barrier WITHOUT the vmcnt(0) drain __syncthreads() emits: LDS correctness only
// needs lgkmcnt(0). Prefetched global loads stay in flight across the barrier.
// Composition per the verified 8-phase template: explicit lgkm wait, sched_barrier
// to pin ordering (rule #18), then the convergent builtin s_barrier (no vmcnt drain).
__device__ __forceinline__ void barrier_lgkm() {
    asm volatile("s_waitcnt lgkmcnt(0)" ::: "memory");
    __builtin_amdgcn_sched_barrier(0);
    __builtin_amdgcn_s_barrier();
}

// ---------------------------------------------------------------------------
// Kernel 1a: partial KV[d][m] = sum_n phi(K[n,d]) * V[n,m], partial Ksum.
// grid (64 bh, 16 s), 256 threads. MFMA 16x16x32_f16, 4 tiles/wave.
// v3: 2-chunk-deep register prefetch (sets A/B) + lgkm-only barriers so the
// global load stream never drains at a barrier. Straight-line 4-chunk schedule.
// (v2 bug fixed: COMPUTE takes the LDS buffer index (chunk&1), NOT the chunk
//  number — COMPUTE(2)/COMPUTE(3) read past the 2-buffer pool -> NaN.)
// ---------------------------------------------------------------------------
__global__ __launch_bounds__(256) void k_kvpart(const float* __restrict__ K,
                                                const float* __restrict__ V,
                                                float* __restrict__ kvpart,
                                                float* __restrict__ kspart) {
    const int bh = blockIdx.x, s = blockIdx.y;
    const int b = bh >> 4, h = bh & 15;
    const int t = threadIdx.x, w = t >> 6, lane = t & 63;
    const int rp = t >> 4, c4 = t & 15;

    __shared__ __align__(16) _Float16 pool[2 * 2 * 64 * ST_];   // 36864 B
    __shared__ float ksred[4][64];

    const f4v* Kf4 = (const f4v*)K;
    const f4v* Vf4 = (const f4v*)V;

    f4v kA[4], vA[4], kB[4], vB[4];

    auto LOADX = [&](f4v* kreg, f4v* vreg, int chunk) {
        const int n0 = s * (N_ / S_) + chunk * 64;
        size_t g = (size_t)(b * N_ + n0 + 4 * rp) * 256 + h * 16 + c4;
        kreg[0] = Kf4[g];       kreg[1] = Kf4[g + 256];
        kreg[2] = Kf4[g + 512]; kreg[3] = Kf4[g + 768];
        vreg[0] = Vf4[g];       vreg[1] = Vf4[g + 256];
        vreg[2] = Vf4[g + 512]; vreg[3] = Vf4[g + 768];
    };
    auto STOREX = [&](const f4v* kreg, const f4v* vreg, int buf) {
        _Float16* Kt = pool + buf * (2 * 64 * ST_);
        _Float16* Vt = Kt + 64 * ST_;
#pragma unroll
        for (int dj = 0; dj < 4; ++dj) {
            int d = 4 * c4 + dj;
            h2 lo, hi;
            lo.x = (_Float16)phi(kreg[0][dj]); lo.y = (_Float16)phi(kreg[1][dj]);
            hi.x = (_Float16)phi(kreg[2][dj]); hi.y = (_Float16)phi(kreg[3][dj]);
            st_h2x2(&Kt[d * ST_ + 4 * rp], lo, hi);
            lo.x = (_Float16)vreg[0][dj]; lo.y = (_Float16)vreg[1][dj];
            hi.x = (_Float16)vreg[2][dj]; hi.y = (_Float16)vreg[3][dj];
            st_h2x2(&Vt[d * ST_ + 4 * rp], lo, hi);
        }
    };

    const int td0 = 2 * (w >> 1);     // d-tile pair base (tiles of 16)
    const int tj0 = 2 * (w & 1);      // m-tile pair base
    const int rA  = lane & 15;
    const int fo  = (lane >> 4) * 8;  // k-offset within a 32-step

    f4v acc[2][2];
#pragma unroll
    for (int a = 0; a < 2; ++a)
#pragma unroll
        for (int bb = 0; bb < 2; ++bb) acc[a][bb] = (f4v){0.f, 0.f, 0.f, 0.f};
    float ksum_acc = 0.f;
    h2 one2; one2.x = (_Float16)1.0f; one2.y = (_Float16)1.0f;

    auto COMPUTE = [&](int buf) {
        const _Float16* Kt = pool + buf * (2 * 64 * ST_);
        const _Float16* Vt = Kt + 64 * ST_;
#pragma unroll
        for (int ks = 0; ks < 2; ++ks) {
            h8 a0 = ld_h8(&Kt[(16 * (td0 + 0) + rA) * ST_ + ks * 32 + fo]);
            h8 a1 = ld_h8(&Kt[(16 * (td0 + 1) + rA) * ST_ + ks * 32 + fo]);
            h8 b0 = ld_h8(&Vt[(16 * (tj0 + 0) + rA) * ST_ + ks * 32 + fo]);
            h8 b1 = ld_h8(&Vt[(16 * (tj0 + 1) + rA) * ST_ + ks * 32 + fo]);
            acc[0][0] = __builtin_amdgcn_mfma_f32_16x16x32_f16(a0, b0, acc[0][0], 0, 0, 0);
            acc[0][1] = __builtin_amdgcn_mfma_f32_16x16x32_f16(a0, b1, acc[0][1], 0, 0, 0);
            acc[1][0] = __builtin_amdgcn_mfma_f32_16x16x32_f16(a1, b0, acc[1][0], 0, 0, 0);
            acc[1][1] = __builtin_amdgcn_mfma_f32_16x16x32_f16(a1, b1, acc[1][1], 0, 0, 0);
        }
        // Ksum quarter-partials: thread t handles d = t&63, n-quarter = t>>6
        {
            int d = t & 63, qtr = t >> 6;
            H2x4 x0 = ld_h2x4(&Kt[d * ST_ + qtr * 16]);
            H2x4 x1 = ld_h2x4(&Kt[d * ST_ + qtr * 16 + 8]);
#pragma unroll
            for (int i = 0; i < 4; ++i) {
                ksum_acc = fdot2(x0.e[i], one2, ksum_acc);
                ksum_acc = fdot2(x1.e[i], one2, ksum_acc);
            }
        }
    };

    // straight-line pipeline: chunk c uses LDS buf (c&1), reg set (c&1 ? B : A)
    LOADX(kA, vA, 0);
    LOADX(kB, vB, 1);
    STOREX(kA, vA, 0);            // waits only on set-A loads (counted vmcnt)
    barrier_lgkm();
    LOADX(kA, vA, 2);             // refill A while chunk0 computes
    COMPUTE(0);                   // buf 0 = chunk 0
    STOREX(kB, vB, 1);
    barrier_lgkm();
    LOADX(kB, vB, 3);
    COMPUTE(1);                   // buf 1 = chunk 1
    STOREX(kA, vA, 0);
    barrier_lgkm();
    COMPUTE(0);                   // buf 0 = chunk 2
    STOREX(kB, vB, 1);
    barrier_lgkm();
    COMPUTE(1);                   // buf 1 = chunk 3

    // epilogue: direct store of the wave's 4 tiles (C layout: col=lane&15,
    // row=(lane>>4)*4+reg — HW-verified m89)
    float* outp = kvpart + (size_t)(bh * S_ + s) * 4096;
#pragma unroll
    for (int a = 0; a < 2; ++a)
#pragma unroll
        for (int bb = 0; bb < 2; ++bb)
#pragma unroll
            for (int r = 0; r < 4; ++r) {
                int d = 16 * (td0 + a) + (lane >> 4) * 4 + r;
                int m = 16 * (tj0 + bb) + (lane & 15);
                outp[d * 64 + m] = acc[a][bb][r];
            }
    ksred[t >> 6][t & 63] = ksum_acc;
    __syncthreads();
    if (t < 64) {
        kspart[(size_t)(bh * S_ + s) * 64 + t] =
            ksred[0][t] + ksred[1][t] + ksred[2][t] + ksred[3][t];
    }
}

// ---------------------------------------------------------------------------
// Kernel 1b: reduce partials -> KV, Ksum; Mt[j][d] = sum_m KV[d][m]*W[j][h*64+m]
// grid (64 bh, 4 dq) = 256 blocks — each block reduces a 16-row d-slice of the
// partials; 4x the resident waves for the 16 MB reduction read.
// ---------------------------------------------------------------------------
__global__ __launch_bounds__(256) void k_makeM(const float* __restrict__ kvpart,
                                               const float* __restrict__ kspart,
                                               const float* __restrict__ W,
                                               _Float16* __restrict__ Mt,
                                               float* __restrict__ Ksum) {
    const int bh = blockIdx.x, dq = blockIdx.y;
    const int h  = bh & 15;
    const int t  = threadIdx.x;

    __shared__ float KVs[16][68];   // KVs[d - dq*16][m]
    __shared__ float Ws[64][68];    // Ws[j][m]

    const f4v* kv4 = (const f4v*)kvpart;
    const f4v* W4  = (const f4v*)W;

    {   // reduce 16 partial-KV rows over the 16 s-slices: one f4v per thread
        int row = t >> 4, c4 = t & 15;
        f4v r = {0.f, 0.f, 0.f, 0.f};
#pragma unroll 4
        for (int s = 0; s < S_; ++s)
            r += kv4[(size_t)(bh * S_ + s) * 1024 + (dq * 16 + row) * 16 + c4];
        *(f4v*)&KVs[row][c4 * 4] = r;
    }
    for (int idx = t; idx < 1024; idx += 256) {
        int wrow = idx >> 4, wc = idx & 15;
        *(f4v*)&Ws[wrow][wc * 4] = W4[(size_t)wrow * 256 + h * 16 + wc];
    }
    if (dq == 0 && t < 64) {
        float ks = 0.f;
        for (int s = 0; s < S_; ++s) ks += kspart[(size_t)(bh * S_ + s) * 64 + t];
        Ksum[(size_t)bh * 64 + t] = ks;
    }
    __syncthreads();

    // thread -> output j = t>>2 (all 64 j), 4 d's at dl = (t&3)*4
    const int j = t >> 2, dl = (t & 3) * 4;
    float acc[4] = {0.f, 0.f, 0.f, 0.f};
#pragma unroll 4
    for (int m4 = 0; m4 < 16; ++m4) {
        f4v wr  = *(const f4v*)&Ws[j][m4 * 4];
        f4v kv0 = *(const f4v*)&KVs[dl + 0][m4 * 4];
        f4v kv1 = *(const f4v*)&KVs[dl + 1][m4 * 4];
        f4v kv2 = *(const f4v*)&KVs[dl + 2][m4 * 4];
        f4v kv3 = *(const f4v*)&KVs[dl + 3][m4 * 4];
        acc[0] += wr[0] * kv0[0] + wr[1] * kv0[1] + wr[2] * kv0[2] + wr[3] * kv0[3];
        acc[1] += wr[0] * kv1[0] + wr[1] * kv1[1] + wr[2] * kv1[2] + wr[3] * kv1[3];
        acc[2] += wr[0] * kv2[0] + wr[1] * kv2[1] + wr[2] * kv2[2] + wr[3] * kv2[3];
        acc[3] += wr[0] * kv3[0] + wr[1] * kv3[1] + wr[2] * kv3[2] + wr[3] * kv3[3];
    }
    h2 lo, hi;
    lo.x = (_Float16)acc[0]; lo.y = (_Float16)acc[1];
    hi.x = (_Float16)acc[2]; hi.y = (_Float16)acc[3];
    H2x2 pk{lo, hi};
    *(float2*)&Mt[((size_t)bh * 64 + j) * 64 + dq * 16 + dl] =
        __builtin_bit_cast(float2, pk);
}

// ---------------------------------------------------------------------------
// Kernel 2: outpart[hs][b,n,j] = sum_{h in slice} z_h(n) * phiQ_h[n,:] . M_h[:,j]
// grid (64 nc, 4 b, 4 hs), 256 threads; 64 n-rows/block, 4 heads/block.
// lgkm-only barriers — the hh+1 prefetch loads stay in flight across both
// per-iteration barriers instead of being drained.
// ---------------------------------------------------------------------------
__global__ __launch_bounds__(256) void k_out(const float* __restrict__ Q,
                                             const _Float16* __restrict__ Mtg,
                                             const float* __restrict__ Ksum,
                                             float* __restrict__ outpart) {
    const int nc = blockIdx.x, b = blockIdx.y, hs = blockIdx.z;
    const int n0 = nc * 64;
    const int t = threadIdx.x, w = t >> 6, lane = t & 63;
    const int rp4 = t >> 4, c4 = t & 15;

    __shared__ __align__(16) _Float16 pool[2 * 2 * 64 * ST_];   // Qp + Mt per buf
    __shared__ float zz[64];
    __shared__ h2 Kss[2][32];

    const f4v* Qf4 = (const f4v*)Q;

    f4v qr[4], mr[2];
    float ksa = 0.f, ksb = 0.f;
    auto LOAD = [&](int hh) {
        const int h = hs * 4 + hh, bh = b * 16 + h;
        size_t g = (size_t)(b * N_ + n0 + rp4) * 256 + h * 16 + c4;
        qr[0] = Qf4[g];            qr[1] = Qf4[g + 16 * 256];
        qr[2] = Qf4[g + 32 * 256]; qr[3] = Qf4[g + 48 * 256];
        mr[0] = ((const f4v*)Mtg)[(size_t)bh * 512 + t];
        mr[1] = ((const f4v*)Mtg)[(size_t)bh * 512 + t + 256];
        if (t < 32) {
            ksa = Ksum[(size_t)bh * 64 + 2 * t];
            ksb = Ksum[(size_t)bh * 64 + 2 * t + 1];
        }
    };
    auto STORE = [&](int buf) {
        _Float16* Qp = pool + buf * (2 * 64 * ST_);
        _Float16* Mt = Qp + 64 * ST_;
#pragma unroll
        for (int r = 0; r < 4; ++r) {
            int row = rp4 + 16 * r;
            h2 p0, p1;
            p0.x = (_Float16)phi(qr[r][0]); p0.y = (_Float16)phi(qr[r][1]);
            p1.x = (_Float16)phi(qr[r][2]); p1.y = (_Float16)phi(qr[r][3]);
            st_h2x2(&Qp[row * ST_ + 4 * c4], p0, p1);
        }
        *(f4v*)&Mt[(t >> 3) * ST_ + (t & 7) * 8] = mr[0];
        *(f4v*)&Mt[((t + 256) >> 3) * ST_ + (t & 7) * 8] = mr[1];
        if (t < 32) { h2 kk; kk.x = (_Float16)ksa; kk.y = (_Float16)ksb; Kss[buf][t] = kk; }
    };

    const int tn0 = 2 * (w >> 1), tj0 = 2 * (w & 1);
    const int rA = lane & 15, fo = (lane >> 4) * 8;
    float facc[2][2][4] = {{{0.f}}};

    LOAD(0);
    STORE(0);

    for (int hh = 0; hh < 4; ++hh) {
        if (hh + 1 < 4) LOAD(hh + 1);
        barrier_lgkm();
        const int buf = hh & 1;
        const _Float16* Qp = pool + buf * (2 * 64 * ST_);
        const _Float16* Mt = Qp + 64 * ST_;

        if (t < 64) {            // z-denominator for row t
            float zp = 0.f;
#pragma unroll
            for (int c = 0; c < 8; ++c) {
                H2x4 x = ld_h2x4(&Qp[t * ST_ + c * 8]);
#pragma unroll
                for (int i = 0; i < 4; ++i) zp = fdot2(x.e[i], Kss[buf][c * 4 + i], zp);
            }
            zz[t] = 1.0f / (zp + EPS_);
        }
        barrier_lgkm();

        f4v acc[2][2];
#pragma unroll
        for (int a = 0; a < 2; ++a)
#pragma unroll
            for (int bb = 0; bb < 2; ++bb) acc[a][bb] = (f4v){0.f, 0.f, 0.f, 0.f};
#pragma unroll
        for (int ks = 0; ks < 2; ++ks) {
            h8 a0 = ld_h8(&Qp[(16 * (tn0 + 0) + rA) * ST_ + ks * 32 + fo]);
            h8 a1 = ld_h8(&Qp[(16 * (tn0 + 1) + rA) * ST_ + ks * 32 + fo]);
            h8 b0 = ld_h8(&Mt[(16 * (tj0 + 0) + rA) * ST_ + ks * 32 + fo]);
            h8 b1 = ld_h8(&Mt[(16 * (tj0 + 1) + rA) * ST_ + ks * 32 + fo]);
            acc[0][0] = __builtin_amdgcn_mfma_f32_16x16x32_f16(a0, b0, acc[0][0], 0, 0, 0);
            acc[0][1] = __builtin_amdgcn_mfma_f32_16x16x32_f16(a0, b1, acc[0][1], 0, 0, 0);
            acc[1][0] = __builtin_amdgcn_mfma_f32_16x16x32_f16(a1, b0, acc[1][0], 0, 0, 0);
            acc[1][1] = __builtin_amdgcn_mfma_f32_16x16x32_f16(a1, b1, acc[1][1], 0, 0, 0);
        }
#pragma unroll
        for (int a = 0; a < 2; ++a)
#pragma unroll
            for (int r = 0; r < 4; ++r) {
                int row = 16 * (tn0 + a) + (lane >> 4) * 4 + r;
                float z = zz[row];
                facc[a][0][r] += z * acc[a][0][r];
                facc[a][1][r] += z * acc[a][1][r];
            }
        if (hh + 1 < 4) STORE((hh + 1) & 1);
    }

    float* op = outpart + (size_t)hs * (B_ * N_ * 64);
#pragma unroll
    for (int a = 0; a < 2; ++a)
#pragma unroll
        for (int bb = 0; bb < 2; ++bb)
#pragma unroll
            for (int r = 0; r < 4; ++r) {
                int n = 16 * (tn0 + a) + (lane >> 4) * 4 + r;
                int j = 16 * (tj0 + bb) + (lane & 15);
                op[(size_t)(b * N_ + n0 + n) * 64 + j] = facc[a][bb][r];
            }
}

// ---------------------------------------------------------------------------
// Kernel 3: out = bias + sum_hs outpart[hs]
// ---------------------------------------------------------------------------
__global__ __launch_bounds__(256) void k_red(const float* __restrict__ outpart,
                                             const float* __restrict__ bout,
                                             float* __restrict__ out) {
    const int p = blockIdx.x * 256 + threadIdx.x;
    const f4v* P4 = (const f4v*)outpart;
    const f4v* B4 = (const f4v*)bout;
    f4v o = B4[p & 15];
    const int stride = B_ * N_ * 64 / 4;
#pragma unroll
    for (int hs = 0; hs < HS_; ++hs) o += P4[(size_t)hs * stride + p];
    ((f4v*)out)[p] = o;
}

// ---------------------------------------------------------------------------
extern "C" void kernel_launch(void* const* d_in, const int* in_sizes, int n_in,
                              void* d_out, int out_size, void* d_ws, size_t ws_size,
                              hipStream_t stream) {
    const float* q  = (const float*)d_in[0];
    const float* k  = (const float*)d_in[1];
    const float* v  = (const float*)d_in[2];
    const float* W  = (const float*)d_in[3];
    const float* bo = (const float*)d_in[4];
    float* out = (float*)d_out;

    float* ws      = (float*)d_ws;
    float* kvpart  = ws;                                    // 64*16*4096 = 16 MB
    float* kspart  = kvpart + (size_t)BH_ * S_ * 4096;      // 256 KB
    float* Mt      = kspart + (size_t)BH_ * S_ * 64;        // 64*4096 f16 = 512 KB
    float* Ksum    = Mt + (size_t)BH_ * 4096 / 2;           // 16 KB
    float* outpart = Ksum + (size_t)BH_ * 64;               // 4 * 4 MB

    k_kvpart<<<dim3(BH_, S_), 256, 0, stream>>>(k, v, kvpart, kspart);
    k_makeM<<<dim3(BH_, 4), 256, 0, stream>>>(kvpart, kspart, W, (_Float16*)Mt, Ksum);
    k_out<<<dim3(N_ / 64, B_, HS_), 256, 0, stream>>>(q, (const _Float16*)Mt, Ksum, outpart);
    k_red<<<B_ * N_ * 64 / 4 / 256, 256, 0, stream>>>(outpart, bo, out);
}

// Round 3
// 224.974 us; speedup vs baseline: 1.0224x; 1.0043x over previous
//
#include <hip/hip_runtime.h>

#define B_  4
#define N_  4096
#define H_  16
#define BH_ 64
#define S_  16
#define HS_ 4
#define ST_ 72          // f16 stride of LDS tiles: 144 B rows (16B-aligned, even frag banks)
#define EPS_ 1e-6f

typedef _Float16 h2  __attribute__((ext_vector_type(2)));
typedef _Float16 h8  __attribute__((ext_vector_type(8)));
typedef float    f4v __attribute__((ext_vector_type(4)));

struct H2x2 { h2 a, b; };
struct H2x4 { h2 e[4]; };

__device__ __forceinline__ h8 ld_h8(const _Float16* p) {
    f4v r = *(const f4v*)p;                       // ds_read_b128
    return __builtin_bit_cast(h8, r);
}
__device__ __forceinline__ H2x4 ld_h2x4(const _Float16* p) {
    f4v r = *(const f4v*)p;
    return __builtin_bit_cast(H2x4, r);
}
__device__ __forceinline__ void st_h2x2(_Float16* p, h2 a, h2 b) {
    H2x2 t{a, b};
    *(float2*)p = __builtin_bit_cast(float2, t);  // ds_write_b64
}
__device__ __forceinline__ float phi(float x) {
    return x > 0.0f ? x + 1.0f : __expf(x);       // elu(x)+1
}
__device__ __forceinline__ float fdot2(h2 a, h2 b, float c) {
    return __builtin_amdgcn_fdot2(a, b, c, false);
}
// Barrier WITHOUT the vmcnt(0) drain __syncthreads() emits: LDS correctness only
// needs lgkmcnt(0). Prefetched global loads stay in flight across the barrier.
__device__ __forceinline__ void barrier_lgkm() {
    asm volatile("s_waitcnt lgkmcnt(0)" ::: "memory");
    __builtin_amdgcn_sched_barrier(0);
    __builtin_amdgcn_s_barrier();
}

// ---------------------------------------------------------------------------
// Kernel 1a: partial KV[d][m] = sum_n phi(K[n,d]) * V[n,m], partial Ksum.
// grid (64 bh, 16 s), 256 threads. MFMA 16x16x32_f16, 4 tiles/wave.
// v4: __launch_bounds__(256,4) — 4 waves/SIMD is all LDS/grid allow anyway;
// raises the VGPR budget 64->128 so the 2-deep prefetch (64 VGPRs of load
// destinations) survives regalloc instead of being serialized into
// load-pair/waitcnt/reuse sequences (v1-v3 all showed VGPR=60 and identical
// 62us regardless of barrier semantics -> register starvation, not barriers).
// ---------------------------------------------------------------------------
__global__ __launch_bounds__(256, 4) void k_kvpart(const float* __restrict__ K,
                                                   const float* __restrict__ V,
                                                   float* __restrict__ kvpart,
                                                   float* __restrict__ kspart) {
    const int bh = blockIdx.x, s = blockIdx.y;
    const int b = bh >> 4, h = bh & 15;
    const int t = threadIdx.x, w = t >> 6, lane = t & 63;
    const int rp = t >> 4, c4 = t & 15;

    __shared__ __align__(16) _Float16 pool[2 * 2 * 64 * ST_];   // 36864 B
    __shared__ float ksred[4][64];

    const f4v* Kf4 = (const f4v*)K;
    const f4v* Vf4 = (const f4v*)V;

    f4v kA[4], vA[4], kB[4], vB[4];

    auto LOADX = [&](f4v* kreg, f4v* vreg, int chunk) {
        const int n0 = s * (N_ / S_) + chunk * 64;
        size_t g = (size_t)(b * N_ + n0 + 4 * rp) * 256 + h * 16 + c4;
        kreg[0] = Kf4[g];       kreg[1] = Kf4[g + 256];
        kreg[2] = Kf4[g + 512]; kreg[3] = Kf4[g + 768];
        vreg[0] = Vf4[g];       vreg[1] = Vf4[g + 256];
        vreg[2] = Vf4[g + 512]; vreg[3] = Vf4[g + 768];
    };
    auto STOREX = [&](const f4v* kreg, const f4v* vreg, int buf) {
        _Float16* Kt = pool + buf * (2 * 64 * ST_);
        _Float16* Vt = Kt + 64 * ST_;
#pragma unroll
        for (int dj = 0; dj < 4; ++dj) {
            int d = 4 * c4 + dj;
            h2 lo, hi;
            lo.x = (_Float16)phi(kreg[0][dj]); lo.y = (_Float16)phi(kreg[1][dj]);
            hi.x = (_Float16)phi(kreg[2][dj]); hi.y = (_Float16)phi(kreg[3][dj]);
            st_h2x2(&Kt[d * ST_ + 4 * rp], lo, hi);
            lo.x = (_Float16)vreg[0][dj]; lo.y = (_Float16)vreg[1][dj];
            hi.x = (_Float16)vreg[2][dj]; hi.y = (_Float16)vreg[3][dj];
            st_h2x2(&Vt[d * ST_ + 4 * rp], lo, hi);
        }
    };

    const int td0 = 2 * (w >> 1);     // d-tile pair base (tiles of 16)
    const int tj0 = 2 * (w & 1);      // m-tile pair base
    const int rA  = lane & 15;
    const int fo  = (lane >> 4) * 8;  // k-offset within a 32-step

    f4v acc[2][2];
#pragma unroll
    for (int a = 0; a < 2; ++a)
#pragma unroll
        for (int bb = 0; bb < 2; ++bb) acc[a][bb] = (f4v){0.f, 0.f, 0.f, 0.f};
    float ksum_acc = 0.f;
    h2 one2; one2.x = (_Float16)1.0f; one2.y = (_Float16)1.0f;

    auto COMPUTE = [&](int buf) {
        const _Float16* Kt = pool + buf * (2 * 64 * ST_);
        const _Float16* Vt = Kt + 64 * ST_;
#pragma unroll
        for (int ks = 0; ks < 2; ++ks) {
            h8 a0 = ld_h8(&Kt[(16 * (td0 + 0) + rA) * ST_ + ks * 32 + fo]);
            h8 a1 = ld_h8(&Kt[(16 * (td0 + 1) + rA) * ST_ + ks * 32 + fo]);
            h8 b0 = ld_h8(&Vt[(16 * (tj0 + 0) + rA) * ST_ + ks * 32 + fo]);
            h8 b1 = ld_h8(&Vt[(16 * (tj0 + 1) + rA) * ST_ + ks * 32 + fo]);
            acc[0][0] = __builtin_amdgcn_mfma_f32_16x16x32_f16(a0, b0, acc[0][0], 0, 0, 0);
            acc[0][1] = __builtin_amdgcn_mfma_f32_16x16x32_f16(a0, b1, acc[0][1], 0, 0, 0);
            acc[1][0] = __builtin_amdgcn_mfma_f32_16x16x32_f16(a1, b0, acc[1][0], 0, 0, 0);
            acc[1][1] = __builtin_amdgcn_mfma_f32_16x16x32_f16(a1, b1, acc[1][1], 0, 0, 0);
        }
        // Ksum quarter-partials: thread t handles d = t&63, n-quarter = t>>6
        {
            int d = t & 63, qtr = t >> 6;
            H2x4 x0 = ld_h2x4(&Kt[d * ST_ + qtr * 16]);
            H2x4 x1 = ld_h2x4(&Kt[d * ST_ + qtr * 16 + 8]);
#pragma unroll
            for (int i = 0; i < 4; ++i) {
                ksum_acc = fdot2(x0.e[i], one2, ksum_acc);
                ksum_acc = fdot2(x1.e[i], one2, ksum_acc);
            }
        }
    };

    // straight-line pipeline: chunk c uses LDS buf (c&1), reg set (c&1 ? B : A)
    LOADX(kA, vA, 0);
    LOADX(kB, vB, 1);
    STOREX(kA, vA, 0);            // waits only on set-A loads (counted vmcnt)
    barrier_lgkm();
    LOADX(kA, vA, 2);             // refill A while chunk0 computes
    COMPUTE(0);                   // buf 0 = chunk 0
    STOREX(kB, vB, 1);
    barrier_lgkm();
    LOADX(kB, vB, 3);
    COMPUTE(1);                   // buf 1 = chunk 1
    STOREX(kA, vA, 0);
    barrier_lgkm();
    COMPUTE(0);                   // buf 0 = chunk 2
    STOREX(kB, vB, 1);
    barrier_lgkm();
    COMPUTE(1);                   // buf 1 = chunk 3

    // epilogue: direct store of the wave's 4 tiles (C layout: col=lane&15,
    // row=(lane>>4)*4+reg — HW-verified m89)
    float* outp = kvpart + (size_t)(bh * S_ + s) * 4096;
#pragma unroll
    for (int a = 0; a < 2; ++a)
#pragma unroll
        for (int bb = 0; bb < 2; ++bb)
#pragma unroll
            for (int r = 0; r < 4; ++r) {
                int d = 16 * (td0 + a) + (lane >> 4) * 4 + r;
                int m = 16 * (tj0 + bb) + (lane & 15);
                outp[d * 64 + m] = acc[a][bb][r];
            }
    ksred[t >> 6][t & 63] = ksum_acc;
    __syncthreads();
    if (t < 64) {
        kspart[(size_t)(bh * S_ + s) * 64 + t] =
            ksred[0][t] + ksred[1][t] + ksred[2][t] + ksred[3][t];
    }
}

// ---------------------------------------------------------------------------
// Kernel 1b: reduce partials -> KV, Ksum; Mt[j][d] = sum_m KV[d][m]*W[j][h*64+m]
// grid (64 bh, 4 dq) = 256 blocks (1/CU). v4: fully unroll the 16-step
// s-reduction so all 16 loads are in flight before one wait (was unroll-4 ->
// 4 serialized latency exposures at 1 block/CU).
// ---------------------------------------------------------------------------
__global__ __launch_bounds__(256, 4) void k_makeM(const float* __restrict__ kvpart,
                                                  const float* __restrict__ kspart,
                                                  const float* __restrict__ W,
                                                  _Float16* __restrict__ Mt,
                                                  float* __restrict__ Ksum) {
    const int bh = blockIdx.x, dq = blockIdx.y;
    const int h  = bh & 15;
    const int t  = threadIdx.x;

    __shared__ float KVs[16][68];   // KVs[d - dq*16][m]
    __shared__ float Ws[64][68];    // Ws[j][m]

    const f4v* kv4 = (const f4v*)kvpart;
    const f4v* W4  = (const f4v*)W;

    {   // reduce 16 partial-KV rows over the 16 s-slices: one f4v per thread
        int row = t >> 4, c4 = t & 15;
        f4v rr[S_];
#pragma unroll
        for (int s = 0; s < S_; ++s)
            rr[s] = kv4[(size_t)(bh * S_ + s) * 1024 + (dq * 16 + row) * 16 + c4];
        f4v r = {0.f, 0.f, 0.f, 0.f};
#pragma unroll
        for (int s = 0; s < S_; ++s) r += rr[s];
        *(f4v*)&KVs[row][c4 * 4] = r;
    }
    for (int idx = t; idx < 1024; idx += 256) {
        int wrow = idx >> 4, wc = idx & 15;
        *(f4v*)&Ws[wrow][wc * 4] = W4[(size_t)wrow * 256 + h * 16 + wc];
    }
    if (dq == 0 && t < 64) {
        float ksl[S_];
#pragma unroll
        for (int s = 0; s < S_; ++s) ksl[s] = kspart[(size_t)(bh * S_ + s) * 64 + t];
        float ks = 0.f;
#pragma unroll
        for (int s = 0; s < S_; ++s) ks += ksl[s];
        Ksum[(size_t)bh * 64 + t] = ks;
    }
    __syncthreads();

    // thread -> output j = t>>2 (all 64 j), 4 d's at dl = (t&3)*4
    const int j = t >> 2, dl = (t & 3) * 4;
    float acc[4] = {0.f, 0.f, 0.f, 0.f};
#pragma unroll 4
    for (int m4 = 0; m4 < 16; ++m4) {
        f4v wr  = *(const f4v*)&Ws[j][m4 * 4];
        f4v kv0 = *(const f4v*)&KVs[dl + 0][m4 * 4];
        f4v kv1 = *(const f4v*)&KVs[dl + 1][m4 * 4];
        f4v kv2 = *(const f4v*)&KVs[dl + 2][m4 * 4];
        f4v kv3 = *(const f4v*)&KVs[dl + 3][m4 * 4];
        acc[0] += wr[0] * kv0[0] + wr[1] * kv0[1] + wr[2] * kv0[2] + wr[3] * kv0[3];
        acc[1] += wr[0] * kv1[0] + wr[1] * kv1[1] + wr[2] * kv1[2] + wr[3] * kv1[3];
        acc[2] += wr[0] * kv2[0] + wr[1] * kv2[1] + wr[2] * kv2[2] + wr[3] * kv2[3];
        acc[3] += wr[0] * kv3[0] + wr[1] * kv3[1] + wr[2] * kv3[2] + wr[3] * kv3[3];
    }
    h2 lo, hi;
    lo.x = (_Float16)acc[0]; lo.y = (_Float16)acc[1];
    hi.x = (_Float16)acc[2]; hi.y = (_Float16)acc[3];
    H2x2 pk{lo, hi};
    *(float2*)&Mt[((size_t)bh * 64 + j) * 64 + dq * 16 + dl] =
        __builtin_bit_cast(float2, pk);
}

// ---------------------------------------------------------------------------
// Kernel 2: outpart[hs][b,n,j] = sum_{h in slice} z_h(n) * phiQ_h[n,:] . M_h[:,j]
// grid (64 nc, 4 b, 4 hs), 256 threads; 64 n-rows/block, 4 heads/block.
// v4: __launch_bounds__(256,4) for the same register-starvation reason.
// ---------------------------------------------------------------------------
__global__ __launch_bounds__(256, 4) void k_out(const float* __restrict__ Q,
                                                const _Float16* __restrict__ Mtg,
                                                const float* __restrict__ Ksum,
                                                float* __restrict__ outpart) {
    const int nc = blockIdx.x, b = blockIdx.y, hs = blockIdx.z;
    const int n0 = nc * 64;
    const int t = threadIdx.x, w = t >> 6, lane = t & 63;
    const int rp4 = t >> 4, c4 = t & 15;

    __shared__ __align__(16) _Float16 pool[2 * 2 * 64 * ST_];   // Qp + Mt per buf
    __shared__ float zz[64];
    __shared__ h2 Kss[2][32];

    const f4v* Qf4 = (const f4v*)Q;

    f4v qr[4], mr[2];
    float ksa = 0.f, ksb = 0.f;
    auto LOAD = [&](int hh) {
        const int h = hs * 4 + hh, bh = b * 16 + h;
        size_t g = (size_t)(b * N_ + n0 + rp4) * 256 + h * 16 + c4;
        qr[0] = Qf4[g];            qr[1] = Qf4[g + 16 * 256];
        qr[2] = Qf4[g + 32 * 256]; qr[3] = Qf4[g + 48 * 256];
        mr[0] = ((const f4v*)Mtg)[(size_t)bh * 512 + t];
        mr[1] = ((const f4v*)Mtg)[(size_t)bh * 512 + t + 256];
        if (t < 32) {
            ksa = Ksum[(size_t)bh * 64 + 2 * t];
            ksb = Ksum[(size_t)bh * 64 + 2 * t + 1];
        }
    };
    auto STORE = [&](int buf) {
        _Float16* Qp = pool + buf * (2 * 64 * ST_);
        _Float16* Mt = Qp + 64 * ST_;
#pragma unroll
        for (int r = 0; r < 4; ++r) {
            int row = rp4 + 16 * r;
            h2 p0, p1;
            p0.x = (_Float16)phi(qr[r][0]); p0.y = (_Float16)phi(qr[r][1]);
            p1.x = (_Float16)phi(qr[r][2]); p1.y = (_Float16)phi(qr[r][3]);
            st_h2x2(&Qp[row * ST_ + 4 * c4], p0, p1);
        }
        *(f4v*)&Mt[(t >> 3) * ST_ + (t & 7) * 8] = mr[0];
        *(f4v*)&Mt[((t + 256) >> 3) * ST_ + (t & 7) * 8] = mr[1];
        if (t < 32) { h2 kk; kk.x = (_Float16)ksa; kk.y = (_Float16)ksb; Kss[buf][t] = kk; }
    };

    const int tn0 = 2 * (w >> 1), tj0 = 2 * (w & 1);
    const int rA = lane & 15, fo = (lane >> 4) * 8;
    float facc[2][2][4] = {{{0.f}}};

    LOAD(0);
    STORE(0);

    for (int hh = 0; hh < 4; ++hh) {
        if (hh + 1 < 4) LOAD(hh + 1);
        barrier_lgkm();
        const int buf = hh & 1;
        const _Float16* Qp = pool + buf * (2 * 64 * ST_);
        const _Float16* Mt = Qp + 64 * ST_;

        if (t < 64) {            // z-denominator for row t
            float zp = 0.f;
#pragma unroll
            for (int c = 0; c < 8; ++c) {
                H2x4 x = ld_h2x4(&Qp[t * ST_ + c * 8]);
#pragma unroll
                for (int i = 0; i < 4; ++i) zp = fdot2(x.e[i], Kss[buf][c * 4 + i], zp);
            }
            zz[t] = 1.0f / (zp + EPS_);
        }
        barrier_lgkm();

        f4v acc[2][2];
#pragma unroll
        for (int a = 0; a < 2; ++a)
#pragma unroll
            for (int bb = 0; bb < 2; ++bb) acc[a][bb] = (f4v){0.f, 0.f, 0.f, 0.f};
#pragma unroll
        for (int ks = 0; ks < 2; ++ks) {
            h8 a0 = ld_h8(&Qp[(16 * (tn0 + 0) + rA) * ST_ + ks * 32 + fo]);
            h8 a1 = ld_h8(&Qp[(16 * (tn0 + 1) + rA) * ST_ + ks * 32 + fo]);
            h8 b0 = ld_h8(&Mt[(16 * (tj0 + 0) + rA) * ST_ + ks * 32 + fo]);
            h8 b1 = ld_h8(&Mt[(16 * (tj0 + 1) + rA) * ST_ + ks * 32 + fo]);
            acc[0][0] = __builtin_amdgcn_mfma_f32_16x16x32_f16(a0, b0, acc[0][0], 0, 0, 0);
            acc[0][1] = __builtin_amdgcn_mfma_f32_16x16x32_f16(a0, b1, acc[0][1], 0, 0, 0);
            acc[1][0] = __builtin_amdgcn_mfma_f32_16x16x32_f16(a1, b0, acc[1][0], 0, 0, 0);
            acc[1][1] = __builtin_amdgcn_mfma_f32_16x16x32_f16(a1, b1, acc[1][1], 0, 0, 0);
        }
#pragma unroll
        for (int a = 0; a < 2; ++a)
#pragma unroll
            for (int r = 0; r < 4; ++r) {
                int row = 16 * (tn0 + a) + (lane >> 4) * 4 + r;
                float z = zz[row];
                facc[a][0][r] += z * acc[a][0][r];
                facc[a][1][r] += z * acc[a][1][r];
            }
        if (hh + 1 < 4) STORE((hh + 1) & 1);
    }

    float* op = outpart + (size_t)hs * (B_ * N_ * 64);
#pragma unroll
    for (int a = 0; a < 2; ++a)
#pragma unroll
        for (int bb = 0; bb < 2; ++bb)
#pragma unroll
            for (int r = 0; r < 4; ++r) {
                int n = 16 * (tn0 + a) + (lane >> 4) * 4 + r;
                int j = 16 * (tj0 + bb) + (lane & 15);
                op[(size_t)(b * N_ + n0 + n) * 64 + j] = facc[a][bb][r];
            }
}

// ---------------------------------------------------------------------------
// Kernel 3: out = bias + sum_hs outpart[hs]
// ---------------------------------------------------------------------------
__global__ __launch_bounds__(256, 4) void k_red(const float* __restrict__ outpart,
                                                const float* __restrict__ bout,
                                                float* __restrict__ out) {
    const int p = blockIdx.x * 256 + threadIdx.x;
    const f4v* P4 = (const f4v*)outpart;
    const f4v* B4 = (const f4v*)bout;
    f4v o = B4[p & 15];
    const int stride = B_ * N_ * 64 / 4;
    f4v pr[HS_];
#pragma unroll
    for (int hs = 0; hs < HS_; ++hs) pr[hs] = P4[(size_t)hs * stride + p];
#pragma unroll
    for (int hs = 0; hs < HS_; ++hs) o += pr[hs];
    ((f4v*)out)[p] = o;
}

// ---------------------------------------------------------------------------
extern "C" void kernel_launch(void* const* d_in, const int* in_sizes, int n_in,
                              void* d_out, int out_size, void* d_ws, size_t ws_size,
                              hipStream_t stream) {
    const float* q  = (const float*)d_in[0];
    const float* k  = (const float*)d_in[1];
    const float* v  = (const float*)d_in[2];
    const float* W  = (const float*)d_in[3];
    const float* bo = (const float*)d_in[4];
    float* out = (float*)d_out;

    float* ws      = (float*)d_ws;
    float* kvpart  = ws;                                    // 64*16*4096 = 16 MB
    float* kspart  = kvpart + (size_t)BH_ * S_ * 4096;      // 256 KB
    float* Mt      = kspart + (size_t)BH_ * S_ * 64;        // 64*4096 f16 = 512 KB
    float* Ksum    = Mt + (size_t)BH_ * 4096 / 2;           // 16 KB
    float* outpart = Ksum + (size_t)BH_ * 64;               // 4 * 4 MB

    k_kvpart<<<dim3(BH_, S_), 256, 0, stream>>>(k, v, kvpart, kspart);
    k_makeM<<<dim3(BH_, 4), 256, 0, stream>>>(kvpart, kspart, W, (_Float16*)Mt, Ksum);
    k_out<<<dim3(N_ / 64, B_, HS_), 256, 0, stream>>>(q, (const _Float16*)Mt, Ksum, outpart);
    k_red<<<B_ * N_ * 64 / 4 / 256, 256, 0, stream>>>(outpart, bo, out);
}

// Round 4
// 221.981 us; speedup vs baseline: 1.0361x; 1.0135x over previous
//
#include <hip/hip_runtime.h>

#define B_  4
#define N_  4096
#define H_  16
#define BH_ 64
#define S_  16
#define HS_ 4
#define ST_ 72          // f16 stride of k_out LDS tiles (unchanged)
#define EPS_ 1e-6f

// k_kvpart v5 LDS geometry: per head/tensor tile [64 d][40 n] f16 + 48 B pad
#define NST_ 40
#define TSH_ 2584       // f16 per tile: 64*40 + 24 (=48 B pad, keeps 16B align)
#define BUFH_ (8 * TSH_)  // 4 heads x {K,V}

typedef _Float16 h2  __attribute__((ext_vector_type(2)));
typedef _Float16 h8  __attribute__((ext_vector_type(8)));
typedef float    f4v __attribute__((ext_vector_type(4)));

struct H2x2 { h2 a, b; };
struct H2x4 { h2 e[4]; };

__device__ __forceinline__ h8 ld_h8(const _Float16* p) {
    f4v r = *(const f4v*)p;                       // ds_read_b128
    return __builtin_bit_cast(h8, r);
}
__device__ __forceinline__ H2x4 ld_h2x4(const _Float16* p) {
    f4v r = *(const f4v*)p;
    return __builtin_bit_cast(H2x4, r);
}
__device__ __forceinline__ void st_h2x2(_Float16* p, h2 a, h2 b) {
    H2x2 t{a, b};
    *(float2*)p = __builtin_bit_cast(float2, t);  // ds_write_b64
}
__device__ __forceinline__ float phi(float x) {
    return x > 0.0f ? x + 1.0f : __expf(x);       // elu(x)+1
}
__device__ __forceinline__ float fdot2(h2 a, h2 b, float c) {
    return __builtin_amdgcn_fdot2(a, b, c, false);
}
// Barrier without the vmcnt(0) drain __syncthreads() emits.
__device__ __forceinline__ void barrier_lgkm() {
    asm volatile("s_waitcnt lgkmcnt(0)" ::: "memory");
    __builtin_amdgcn_sched_barrier(0);
    __builtin_amdgcn_s_barrier();
}

// ---------------------------------------------------------------------------
// Kernel 1a v5: partial KV[d][m] = sum_n phi(K[n,d]) * V[n,m] + partial Ksum.
// DRAM-locality restructure: one block = 4 heads x 256 rows, so every
// wave-level load instruction reads 1 KB CONTIGUOUS (one full row slice of 4
// heads) instead of the old 256-B head-slices strided 4 KB (which measured
// ~1.5 TB/s = 24% of achievable; barriers & VGPR budget both falsified as
// causes). grid (16 s, 4 hq, 4 b), 512 threads = 8 waves (wave-pair/head).
// 8 chunks x 32 rows, 2-deep reg prefetch, LDS double buffer, lgkm barriers.
// Ksum via MFMA with a ones-B-fragment (matrix pipe is idle anyway).
// Output layout of kvpart/kspart unchanged -> downstream kernels untouched.
// ---------------------------------------------------------------------------
__global__ __launch_bounds__(512, 2) void k_kvpart(const float* __restrict__ K,
                                                   const float* __restrict__ V,
                                                   float* __restrict__ kvpart,
                                                   float* __restrict__ kspart) {
    const int s = blockIdx.x, hq = blockIdx.y, b = blockIdx.z;
    const int t = threadIdx.x, wv = t >> 6, lane = t & 63;
    const int hp = lane >> 4;         // head index for staging (0..3)
    const int l15 = lane & 15;

    __shared__ __align__(16) _Float16 pool[2 * BUFH_];   // 82688 B

    const f4v* Kf4 = (const f4v*)K;
    const f4v* Vf4 = (const f4v*)V;

    f4v kA[4], vA[4], kB[4], vB[4];

    // chunk = 32 rows; wave wv owns rows 4wv..4wv+3; lane = col4 (1 KB/row)
    auto LOADX = [&](f4v* kreg, f4v* vreg, int chunk) {
        const int n0 = s * 256 + chunk * 32 + 4 * wv;
        size_t g = (size_t)(b * N_ + n0) * 256 + hq * 64 + lane;
        kreg[0] = Kf4[g];       kreg[1] = Kf4[g + 256];
        kreg[2] = Kf4[g + 512]; kreg[3] = Kf4[g + 768];
        vreg[0] = Vf4[g];       vreg[1] = Vf4[g + 256];
        vreg[2] = Vf4[g + 512]; vreg[3] = Vf4[g + 768];
    };
    // transpose-stage: thread holds 4 consecutive rows (n=4wv..+3) of 4
    // consecutive f32 cols (d = 4*l15..+3) of head hp -> 4x b64 per tensor
    auto STOREX = [&](const f4v* kreg, const f4v* vreg, int buf) {
        _Float16* Kt = pool + buf * BUFH_ + (hp * 2) * TSH_;
        _Float16* Vt = Kt + TSH_;
        const int nn = 4 * wv;
#pragma unroll
        for (int dj = 0; dj < 4; ++dj) {
            int d = 4 * l15 + dj;
            h2 lo, hi;
            lo.x = (_Float16)phi(kreg[0][dj]); lo.y = (_Float16)phi(kreg[1][dj]);
            hi.x = (_Float16)phi(kreg[2][dj]); hi.y = (_Float16)phi(kreg[3][dj]);
            st_h2x2(&Kt[d * NST_ + nn], lo, hi);
            lo.x = (_Float16)vreg[0][dj]; lo.y = (_Float16)vreg[1][dj];
            hi.x = (_Float16)vreg[2][dj]; hi.y = (_Float16)vreg[3][dj];
            st_h2x2(&Vt[d * NST_ + nn], lo, hi);
        }
    };

    // MFMA assignment: head hh = wv>>1; d-half = wv&1 (rows 32*dhalf..+31)
    const int hh = wv >> 1, dhalf = wv & 1;
    const int rA = l15;
    const int fo = (lane >> 4) * 8;   // n-offset within the 32-contraction

    f4v acc[2][4];                    // [d-tile][m-tile]
#pragma unroll
    for (int a = 0; a < 2; ++a)
#pragma unroll
        for (int m = 0; m < 4; ++m) acc[a][m] = (f4v){0.f, 0.f, 0.f, 0.f};
    f4v accK[2];
    accK[0] = (f4v){0.f, 0.f, 0.f, 0.f};
    accK[1] = (f4v){0.f, 0.f, 0.f, 0.f};
    h8 ones;
#pragma unroll
    for (int i = 0; i < 8; ++i) ones[i] = (_Float16)1.0f;

    auto COMPUTE = [&](int buf) {
        const _Float16* Kt = pool + buf * BUFH_ + (hh * 2) * TSH_;
        const _Float16* Vt = Kt + TSH_;
        h8 a0 = ld_h8(&Kt[(32 * dhalf + rA) * NST_ + fo]);
        h8 a1 = ld_h8(&Kt[(32 * dhalf + 16 + rA) * NST_ + fo]);
        h8 b0 = ld_h8(&Vt[(rA) * NST_ + fo]);
        h8 b1 = ld_h8(&Vt[(16 + rA) * NST_ + fo]);
        h8 b2 = ld_h8(&Vt[(32 + rA) * NST_ + fo]);
        h8 b3 = ld_h8(&Vt[(48 + rA) * NST_ + fo]);
        acc[0][0] = __builtin_amdgcn_mfma_f32_16x16x32_f16(a0, b0, acc[0][0], 0, 0, 0);
        acc[0][1] = __builtin_amdgcn_mfma_f32_16x16x32_f16(a0, b1, acc[0][1], 0, 0, 0);
        acc[0][2] = __builtin_amdgcn_mfma_f32_16x16x32_f16(a0, b2, acc[0][2], 0, 0, 0);
        acc[0][3] = __builtin_amdgcn_mfma_f32_16x16x32_f16(a0, b3, acc[0][3], 0, 0, 0);
        acc[1][0] = __builtin_amdgcn_mfma_f32_16x16x32_f16(a1, b0, acc[1][0], 0, 0, 0);
        acc[1][1] = __builtin_amdgcn_mfma_f32_16x16x32_f16(a1, b1, acc[1][1], 0, 0, 0);
        acc[1][2] = __builtin_amdgcn_mfma_f32_16x16x32_f16(a1, b2, acc[1][2], 0, 0, 0);
        acc[1][3] = __builtin_amdgcn_mfma_f32_16x16x32_f16(a1, b3, acc[1][3], 0, 0, 0);
        accK[0]   = __builtin_amdgcn_mfma_f32_16x16x32_f16(a0, ones, accK[0], 0, 0, 0);
        accK[1]   = __builtin_amdgcn_mfma_f32_16x16x32_f16(a1, ones, accK[1], 0, 0, 0);
    };

    // 8-chunk straight-line pipeline; chunk c: LDS buf c&1, reg set c&1?B:A
    LOADX(kA, vA, 0);
    LOADX(kB, vB, 1);
    STOREX(kA, vA, 0);
    barrier_lgkm();
    LOADX(kA, vA, 2); COMPUTE(0); STOREX(kB, vB, 1); barrier_lgkm();
    LOADX(kB, vB, 3); COMPUTE(1); STOREX(kA, vA, 0); barrier_lgkm();
    LOADX(kA, vA, 4); COMPUTE(0); STOREX(kB, vB, 1); barrier_lgkm();
    LOADX(kB, vB, 5); COMPUTE(1); STOREX(kA, vA, 0); barrier_lgkm();
    LOADX(kA, vA, 6); COMPUTE(0); STOREX(kB, vB, 1); barrier_lgkm();
    LOADX(kB, vB, 7); COMPUTE(1); STOREX(kA, vA, 0); barrier_lgkm();
    COMPUTE(0); STOREX(kB, vB, 1); barrier_lgkm();
    COMPUTE(1);

    // epilogue (C layout: col=lane&15, row=(lane>>4)*4+reg — HW-verified m89)
    const int bh = b * 16 + hq * 4 + hh;
    float* outp = kvpart + (size_t)(bh * S_ + s) * 4096;
#pragma unroll
    for (int a = 0; a < 2; ++a)
#pragma unroll
        for (int m = 0; m < 4; ++m)
#pragma unroll
            for (int r = 0; r < 4; ++r) {
                int d = 32 * dhalf + 16 * a + hp * 4 + r;
                int mm = 16 * m + l15;
                outp[d * 64 + mm] = acc[a][m][r];
            }
    if (l15 == 0) {
        float* ksp = kspart + (size_t)(bh * S_ + s) * 64;
#pragma unroll
        for (int a = 0; a < 2; ++a)
#pragma unroll
            for (int r = 0; r < 4; ++r) {
                int d = 32 * dhalf + 16 * a + hp * 4 + r;
                ksp[d] = accK[a][r];
            }
    }
}

// ---------------------------------------------------------------------------
// Kernel 1b: reduce partials -> KV, Ksum; Mt[j][d] = sum_m KV[d][m]*W[j][h*64+m]
// grid (64 bh, 4 dq) = 256 blocks; fully-unrolled 16-step s-reduction.
// ---------------------------------------------------------------------------
__global__ __launch_bounds__(256, 4) void k_makeM(const float* __restrict__ kvpart,
                                                  const float* __restrict__ kspart,
                                                  const float* __restrict__ W,
                                                  _Float16* __restrict__ Mt,
                                                  float* __restrict__ Ksum) {
    const int bh = blockIdx.x, dq = blockIdx.y;
    const int h  = bh & 15;
    const int t  = threadIdx.x;

    __shared__ float KVs[16][68];   // KVs[d - dq*16][m]
    __shared__ float Ws[64][68];    // Ws[j][m]

    const f4v* kv4 = (const f4v*)kvpart;
    const f4v* W4  = (const f4v*)W;

    {   // reduce 16 partial-KV rows over the 16 s-slices: one f4v per thread
        int row = t >> 4, c4 = t & 15;
        f4v rr[S_];
#pragma unroll
        for (int s = 0; s < S_; ++s)
            rr[s] = kv4[(size_t)(bh * S_ + s) * 1024 + (dq * 16 + row) * 16 + c4];
        f4v r = {0.f, 0.f, 0.f, 0.f};
#pragma unroll
        for (int s = 0; s < S_; ++s) r += rr[s];
        *(f4v*)&KVs[row][c4 * 4] = r;
    }
    for (int idx = t; idx < 1024; idx += 256) {
        int wrow = idx >> 4, wc = idx & 15;
        *(f4v*)&Ws[wrow][wc * 4] = W4[(size_t)wrow * 256 + h * 16 + wc];
    }
    if (dq == 0 && t < 64) {
        float ksl[S_];
#pragma unroll
        for (int s = 0; s < S_; ++s) ksl[s] = kspart[(size_t)(bh * S_ + s) * 64 + t];
        float ks = 0.f;
#pragma unroll
        for (int s = 0; s < S_; ++s) ks += ksl[s];
        Ksum[(size_t)bh * 64 + t] = ks;
    }
    __syncthreads();

    // thread -> output j = t>>2 (all 64 j), 4 d's at dl = (t&3)*4
    const int j = t >> 2, dl = (t & 3) * 4;
    float acc[4] = {0.f, 0.f, 0.f, 0.f};
#pragma unroll 4
    for (int m4 = 0; m4 < 16; ++m4) {
        f4v wr  = *(const f4v*)&Ws[j][m4 * 4];
        f4v kv0 = *(const f4v*)&KVs[dl + 0][m4 * 4];
        f4v kv1 = *(const f4v*)&KVs[dl + 1][m4 * 4];
        f4v kv2 = *(const f4v*)&KVs[dl + 2][m4 * 4];
        f4v kv3 = *(const f4v*)&KVs[dl + 3][m4 * 4];
        acc[0] += wr[0] * kv0[0] + wr[1] * kv0[1] + wr[2] * kv0[2] + wr[3] * kv0[3];
        acc[1] += wr[0] * kv1[0] + wr[1] * kv1[1] + wr[2] * kv1[2] + wr[3] * kv1[3];
        acc[2] += wr[0] * kv2[0] + wr[1] * kv2[1] + wr[2] * kv2[2] + wr[3] * kv2[3];
        acc[3] += wr[0] * kv3[0] + wr[1] * kv3[1] + wr[2] * kv3[2] + wr[3] * kv3[3];
    }
    h2 lo, hi;
    lo.x = (_Float16)acc[0]; lo.y = (_Float16)acc[1];
    hi.x = (_Float16)acc[2]; hi.y = (_Float16)acc[3];
    H2x2 pk{lo, hi};
    *(float2*)&Mt[((size_t)bh * 64 + j) * 64 + dq * 16 + dl] =
        __builtin_bit_cast(float2, pk);
}

// ---------------------------------------------------------------------------
// Kernel 2: outpart[hs][b,n,j] = sum_{h in slice} z_h(n) * phiQ_h[n,:] . M_h[:,j]
// grid (64 nc, 4 b, 4 hs), 256 threads; 64 n-rows/block, 4 heads/block.
// ---------------------------------------------------------------------------
__global__ __launch_bounds__(256, 4) void k_out(const float* __restrict__ Q,
                                                const _Float16* __restrict__ Mtg,
                                                const float* __restrict__ Ksum,
                                                float* __restrict__ outpart) {
    const int nc = blockIdx.x, b = blockIdx.y, hs = blockIdx.z;
    const int n0 = nc * 64;
    const int t = threadIdx.x, w = t >> 6, lane = t & 63;
    const int rp4 = t >> 4, c4 = t & 15;

    __shared__ __align__(16) _Float16 pool[2 * 2 * 64 * ST_];   // Qp + Mt per buf
    __shared__ float zz[64];
    __shared__ h2 Kss[2][32];

    const f4v* Qf4 = (const f4v*)Q;

    f4v qr[4], mr[2];
    float ksa = 0.f, ksb = 0.f;
    auto LOAD = [&](int hh) {
        const int h = hs * 4 + hh, bh = b * 16 + h;
        size_t g = (size_t)(b * N_ + n0 + rp4) * 256 + h * 16 + c4;
        qr[0] = Qf4[g];            qr[1] = Qf4[g + 16 * 256];
        qr[2] = Qf4[g + 32 * 256]; qr[3] = Qf4[g + 48 * 256];
        mr[0] = ((const f4v*)Mtg)[(size_t)bh * 512 + t];
        mr[1] = ((const f4v*)Mtg)[(size_t)bh * 512 + t + 256];
        if (t < 32) {
            ksa = Ksum[(size_t)bh * 64 + 2 * t];
            ksb = Ksum[(size_t)bh * 64 + 2 * t + 1];
        }
    };
    auto STORE = [&](int buf) {
        _Float16* Qp = pool + buf * (2 * 64 * ST_);
        _Float16* Mt = Qp + 64 * ST_;
#pragma unroll
        for (int r = 0; r < 4; ++r) {
            int row = rp4 + 16 * r;
            h2 p0, p1;
            p0.x = (_Float16)phi(qr[r][0]); p0.y = (_Float16)phi(qr[r][1]);
            p1.x = (_Float16)phi(qr[r][2]); p1.y = (_Float16)phi(qr[r][3]);
            st_h2x2(&Qp[row * ST_ + 4 * c4], p0, p1);
        }
        *(f4v*)&Mt[(t >> 3) * ST_ + (t & 7) * 8] = mr[0];
        *(f4v*)&Mt[((t + 256) >> 3) * ST_ + (t & 7) * 8] = mr[1];
        if (t < 32) { h2 kk; kk.x = (_Float16)ksa; kk.y = (_Float16)ksb; Kss[buf][t] = kk; }
    };

    const int tn0 = 2 * (w >> 1), tj0 = 2 * (w & 1);
    const int rA = lane & 15, fo = (lane >> 4) * 8;
    float facc[2][2][4] = {{{0.f}}};

    LOAD(0);
    STORE(0);

    for (int hh = 0; hh < 4; ++hh) {
        if (hh + 1 < 4) LOAD(hh + 1);
        barrier_lgkm();
        const int buf = hh & 1;
        const _Float16* Qp = pool + buf * (2 * 64 * ST_);
        const _Float16* Mt = Qp + 64 * ST_;

        if (t < 64) {            // z-denominator for row t
            float zp = 0.f;
#pragma unroll
            for (int c = 0; c < 8; ++c) {
                H2x4 x = ld_h2x4(&Qp[t * ST_ + c * 8]);
#pragma unroll
                for (int i = 0; i < 4; ++i) zp = fdot2(x.e[i], Kss[buf][c * 4 + i], zp);
            }
            zz[t] = 1.0f / (zp + EPS_);
        }
        barrier_lgkm();

        f4v acc[2][2];
#pragma unroll
        for (int a = 0; a < 2; ++a)
#pragma unroll
            for (int bb = 0; bb < 2; ++bb) acc[a][bb] = (f4v){0.f, 0.f, 0.f, 0.f};
#pragma unroll
        for (int ks = 0; ks < 2; ++ks) {
            h8 a0 = ld_h8(&Qp[(16 * (tn0 + 0) + rA) * ST_ + ks * 32 + fo]);
            h8 a1 = ld_h8(&Qp[(16 * (tn0 + 1) + rA) * ST_ + ks * 32 + fo]);
            h8 b0 = ld_h8(&Mt[(16 * (tj0 + 0) + rA) * ST_ + ks * 32 + fo]);
            h8 b1 = ld_h8(&Mt[(16 * (tj0 + 1) + rA) * ST_ + ks * 32 + fo]);
            acc[0][0] = __builtin_amdgcn_mfma_f32_16x16x32_f16(a0, b0, acc[0][0], 0, 0, 0);
            acc[0][1] = __builtin_amdgcn_mfma_f32_16x16x32_f16(a0, b1, acc[0][1], 0, 0, 0);
            acc[1][0] = __builtin_amdgcn_mfma_f32_16x16x32_f16(a1, b0, acc[1][0], 0, 0, 0);
            acc[1][1] = __builtin_amdgcn_mfma_f32_16x16x32_f16(a1, b1, acc[1][1], 0, 0, 0);
        }
#pragma unroll
        for (int a = 0; a < 2; ++a)
#pragma unroll
            for (int r = 0; r < 4; ++r) {
                int row = 16 * (tn0 + a) + (lane >> 4) * 4 + r;
                float z = zz[row];
                facc[a][0][r] += z * acc[a][0][r];
                facc[a][1][r] += z * acc[a][1][r];
            }
        if (hh + 1 < 4) STORE((hh + 1) & 1);
    }

    float* op = outpart + (size_t)hs * (B_ * N_ * 64);
#pragma unroll
    for (int a = 0; a < 2; ++a)
#pragma unroll
        for (int bb = 0; bb < 2; ++bb)
#pragma unroll
            for (int r = 0; r < 4; ++r) {
                int n = 16 * (tn0 + a) + (lane >> 4) * 4 + r;
                int j = 16 * (tj0 + bb) + (lane & 15);
                op[(size_t)(b * N_ + n0 + n) * 64 + j] = facc[a][bb][r];
            }
}

// ---------------------------------------------------------------------------
// Kernel 3: out = bias + sum_hs outpart[hs]
// ---------------------------------------------------------------------------
__global__ __launch_bounds__(256, 4) void k_red(const float* __restrict__ outpart,
                                                const float* __restrict__ bout,
                                                float* __restrict__ out) {
    const int p = blockIdx.x * 256 + threadIdx.x;
    const f4v* P4 = (const f4v*)outpart;
    const f4v* B4 = (const f4v*)bout;
    f4v o = B4[p & 15];
    const int stride = B_ * N_ * 64 / 4;
    f4v pr[HS_];
#pragma unroll
    for (int hs = 0; hs < HS_; ++hs) pr[hs] = P4[(size_t)hs * stride + p];
#pragma unroll
    for (int hs = 0; hs < HS_; ++hs) o += pr[hs];
    ((f4v*)out)[p] = o;
}

// ---------------------------------------------------------------------------
extern "C" void kernel_launch(void* const* d_in, const int* in_sizes, int n_in,
                              void* d_out, int out_size, void* d_ws, size_t ws_size,
                              hipStream_t stream) {
    const float* q  = (const float*)d_in[0];
    const float* k  = (const float*)d_in[1];
    const float* v  = (const float*)d_in[2];
    const float* W  = (const float*)d_in[3];
    const float* bo = (const float*)d_in[4];
    float* out = (float*)d_out;

    float* ws      = (float*)d_ws;
    float* kvpart  = ws;                                    // 64*16*4096 = 16 MB
    float* kspart  = kvpart + (size_t)BH_ * S_ * 4096;      // 256 KB
    float* Mt      = kspart + (size_t)BH_ * S_ * 64;        // 64*4096 f16 = 512 KB
    float* Ksum    = Mt + (size_t)BH_ * 4096 / 2;           // 16 KB
    float* outpart = Ksum + (size_t)BH_ * 64;               // 4 * 4 MB

    k_kvpart<<<dim3(S_, 4, 4), 512, 0, stream>>>(k, v, kvpart, kspart);
    k_makeM<<<dim3(BH_, 4), 256, 0, stream>>>(kvpart, kspart, W, (_Float16*)Mt, Ksum);
    k_out<<<dim3(N_ / 64, B_, HS_), 256, 0, stream>>>(q, (const _Float16*)Mt, Ksum, outpart);
    k_red<<<B_ * N_ * 64 / 4 / 256, 256, 0, stream>>>(outpart, bo, out);
}